// Round 3
// baseline (299.859 us; speedup 1.0000x reference)
//
#include <hip/hip_runtime.h>
#include <hip/hip_bf16.h>

#define NN 10000
#define EE 320000
#define DD 128
#define TE 64   // edges (or nodes) per block tile

typedef __attribute__((ext_vector_type(8))) __bf16 bf16x8;
typedef __attribute__((ext_vector_type(4))) float  f32x4;

__device__ __forceinline__ float silu_f(float x) {
    return x / (1.0f + __expf(-x));
}
__device__ __forceinline__ float sigmoid_f(float x) {
    return 1.0f / (1.0f + __expf(-x));
}

__device__ __forceinline__ unsigned short f2bf(float f) {
    unsigned u = __builtin_bit_cast(unsigned, f);
    u += 0x7FFFu + ((u >> 16) & 1u);   // RNE
    return (unsigned short)(u >> 16);
}
__device__ __forceinline__ float bf2f(unsigned short u) {
    return __builtin_bit_cast(float, (unsigned)u << 16);
}

__device__ __forceinline__ float atomic_add_f(float* p, float v) {
    return unsafeAtomicAdd(p, v);
}

// ---------------------------------------------------------------------------
// CSR build: histogram -> scan -> scatter (row-sorted edge permutation)
// ---------------------------------------------------------------------------
__global__ void hist_kernel(const int* __restrict__ ei, int* __restrict__ cnt)
{
    const int e = blockIdx.x * 256 + threadIdx.x;
    if (e < EE) atomicAdd(&cnt[ei[e]], 1);
}

__global__ __launch_bounds__(512)
void scan_kernel(const int* __restrict__ cnt, int* __restrict__ offs)
{
    __shared__ int part[512];
    const int t = threadIdx.x;
    const int base = t * 20;
    int loc[20];
    int s = 0;
#pragma unroll
    for (int i = 0; i < 20; ++i) {
        const int idx = base + i;
        const int v = (idx < NN) ? cnt[idx] : 0;
        loc[i] = s; s += v;
    }
    part[t] = s;
    __syncthreads();
    for (int d = 1; d < 512; d <<= 1) {
        const int v = (t >= d) ? part[t - d] : 0;
        __syncthreads();
        part[t] += v;
        __syncthreads();
    }
    const int pre = (t == 0) ? 0 : part[t - 1];
#pragma unroll
    for (int i = 0; i < 20; ++i) {
        const int idx = base + i;
        if (idx < NN) offs[idx] = pre + loc[i];
    }
    if (t == 511) offs[NN] = pre + s;   // == EE
}

__global__ void scatter_kernel(const int* __restrict__ ei, const int* __restrict__ offs,
                               int* __restrict__ tmp, int* __restrict__ perm)
{
    const int e = blockIdx.x * 256 + threadIdx.x;
    if (e >= EE) return;
    const int r = ei[e];
    const int pos = offs[r] + atomicAdd(&tmp[r], 1);
    perm[pos] = e;
}

// ---------------------------------------------------------------------------
// prep: convert + pack weights into per-lane MFMA B-fragments (bf16).
// Fragment (ct, ks): lane l holds B[k][n], n = ct*16+(l&15), k = ks*32+(l>>4)*8+j.
// ---------------------------------------------------------------------------
__global__ void prep_kernel(const float* __restrict__ We1,
                            const float* __restrict__ We2,
                            const float* __restrict__ Wc1,
                            unsigned short* __restrict__ pW)
{
    const int idx = blockIdx.x * 256 + threadIdx.x;
    if (idx >= 65536) return;
    const float* src; int loc, nks;
    if (idx < 32768)      { src = We1; loc = idx;         nks = 8; }
    else if (idx < 49152) { src = We2; loc = idx - 32768; nks = 4; }
    else                  { src = Wc1; loc = idx - 49152; nks = 4; }
    const int per_ct = nks * 512;
    const int ct = loc / per_ct;
    const int r  = loc % per_ct;
    const int ks = r >> 9;
    const int r2 = r & 511;
    const int ln = r2 >> 3;
    const int j  = r2 & 7;
    const int k  = ks * 32 + (ln >> 4) * 8 + j;
    const int n  = ct * 16 + (ln & 15);
    pW[idx] = f2bf(src[k * DD + n]);
}

// ---------------------------------------------------------------------------
// edge kernel: 64 row-sorted edges/block, 4 waves, MFMA 16x16x32 bf16.
// Wave w owns output cols [32w, 32w+32). Aggregation via block-local
// segmented reduce (rows sorted -> ~2-3 distinct rows per tile).
// ---------------------------------------------------------------------------
__global__ __launch_bounds__(256, 3)
void edge_kernel(const float* __restrict__ h, const int* __restrict__ ei,
                 const float* __restrict__ coord, const int* __restrict__ perm,
                 const float* __restrict__ We1, const float* __restrict__ be1,
                 const float* __restrict__ be2,
                 const float* __restrict__ Wa, const float* __restrict__ ba,
                 const float* __restrict__ bc1, const float* __restrict__ Wc2,
                 const unsigned short* __restrict__ pW,
                 float* __restrict__ agg_h, float* __restrict__ agg_c)
{
    // A-tile buffer: GEMM1 view [64][256] bf16 (512 B rows); reused:
    //   m1 view = bytes [0,16384), ef view = bytes [16384,32768)
    __shared__ __align__(16) unsigned short sAbuf[64 * 256];
    __shared__ __align__(16) float sWred[4][64];
    __shared__ __align__(16) int   sRow[64];
    __shared__ int   sCol[64];
    __shared__ __align__(16) float sRad[64];
    __shared__ __align__(16) float sAtt[64];
    __shared__ float sCd[64][3];

    const int tid  = threadIdx.x;
    const int w    = tid >> 6;
    const int lane = tid & 63;
    const int g    = lane >> 4;
    const int l15  = lane & 15;
    const int e0g  = blockIdx.x * TE;

    char* const sAb = (char*)sAbuf;

    // ---- phase 0: permuted indices, coord diff, radial ----
    if (tid < TE) {
        const int e = perm[e0g + tid];
        const int r = ei[e];
        const int c = ei[EE + e];
        sRow[tid] = r; sCol[tid] = c;
        const float dx = coord[r * 3 + 0] - coord[c * 3 + 0];
        const float dy = coord[r * 3 + 1] - coord[c * 3 + 1];
        const float dz = coord[r * 3 + 2] - coord[c * 3 + 2];
        sCd[tid][0] = dx; sCd[tid][1] = dy; sCd[tid][2] = dz;
        sRad[tid] = dx * dx + dy * dy + dz * dz;
    }
    __syncthreads();

    // ---- phase 1: stage [h[row] | h[col]] as bf16 into swizzled A-tile ----
    {
        const int halfsel = (lane >= 32) ? 1 : 0;
        const int bytec   = (lane & 31) * 8 + halfsel * 256;
#pragma unroll 4
        for (int s = 0; s < 16; ++s) {
            const int e = w * 16 + s;
            const int r = halfsel ? sCol[e] : sRow[e];
            const float4 v = *(const float4*)&h[(size_t)r * DD + (lane & 31) * 4];
            uint2 pk;
            pk.x = (unsigned)f2bf(v.x) | ((unsigned)f2bf(v.y) << 16);
            pk.y = (unsigned)f2bf(v.z) | ((unsigned)f2bf(v.w) << 16);
            *(uint2*)(sAb + e * 512 + (bytec ^ ((e & 7) << 4))) = pk;
        }
    }
    __syncthreads();

    f32x4 acc[4][2];

    // ---- phase 2: GEMM1  m1 = silu(A @ We1 + radial*wr + be1) ----
    {
        float be1c[2], wrc[2];
#pragma unroll
        for (int ctl = 0; ctl < 2; ++ctl) {
            const int col = w * 32 + ctl * 16 + l15;
            be1c[ctl] = be1[col];
            wrc[ctl]  = We1[256 * DD + col];
        }
#pragma unroll
        for (int rt = 0; rt < 4; ++rt) {
            const float4 rad4 = *(const float4*)&sRad[rt * 16 + g * 4];
            const float rr[4] = {rad4.x, rad4.y, rad4.z, rad4.w};
#pragma unroll
            for (int ctl = 0; ctl < 2; ++ctl)
#pragma unroll
                for (int j = 0; j < 4; ++j)
                    acc[rt][ctl][j] = fmaf(rr[j], wrc[ctl], be1c[ctl]);
        }
        const unsigned short* pWe1 = pW;
#pragma unroll 1
        for (int ks = 0; ks < 8; ++ks) {
            bf16x8 a[4];
#pragma unroll
            for (int rt = 0; rt < 4; ++rt) {
                const int row = rt * 16 + l15;
                const int byc = g * 16 + ks * 64;
                a[rt] = *(const bf16x8*)(sAb + row * 512 + (byc ^ ((row & 7) << 4)));
            }
            const bf16x8 b0 = *(const bf16x8*)&pWe1[(((2 * w + 0) * 8 + ks) * 64 + lane) * 8];
            const bf16x8 b1 = *(const bf16x8*)&pWe1[(((2 * w + 1) * 8 + ks) * 64 + lane) * 8];
#pragma unroll
            for (int rt = 0; rt < 4; ++rt) {
                acc[rt][0] = __builtin_amdgcn_mfma_f32_16x16x32_bf16(a[rt], b0, acc[rt][0], 0, 0, 0);
                acc[rt][1] = __builtin_amdgcn_mfma_f32_16x16x32_bf16(a[rt], b1, acc[rt][1], 0, 0, 0);
            }
        }
    }
    __syncthreads();

    // silu -> bf16 -> m1 view (256 B rows, same XOR swizzle)
#pragma unroll
    for (int rt = 0; rt < 4; ++rt)
#pragma unroll
        for (int ctl = 0; ctl < 2; ++ctl)
#pragma unroll
            for (int j = 0; j < 4; ++j) {
                const int row = rt * 16 + g * 4 + j;
                const int col = w * 32 + ctl * 16 + l15;
                *(unsigned short*)(sAb + row * 256 + ((col * 2) ^ ((row & 7) << 4)))
                    = f2bf(silu_f(acc[rt][ctl][j]));
            }
    __syncthreads();

    // ---- phase 3: GEMM2  m = silu(m1 @ We2 + be2) ----
    {
        float be2c[2];
#pragma unroll
        for (int ctl = 0; ctl < 2; ++ctl)
            be2c[ctl] = be2[w * 32 + ctl * 16 + l15];
#pragma unroll
        for (int rt = 0; rt < 4; ++rt)
#pragma unroll
            for (int ctl = 0; ctl < 2; ++ctl)
#pragma unroll
                for (int j = 0; j < 4; ++j)
                    acc[rt][ctl][j] = be2c[ctl];
        const unsigned short* pWe2 = pW + 32768;
#pragma unroll 1
        for (int ks = 0; ks < 4; ++ks) {
            bf16x8 a[4];
#pragma unroll
            for (int rt = 0; rt < 4; ++rt) {
                const int row = rt * 16 + l15;
                const int byc = g * 16 + ks * 64;
                a[rt] = *(const bf16x8*)(sAb + row * 256 + (byc ^ ((row & 7) << 4)));
            }
            const bf16x8 b0 = *(const bf16x8*)&pWe2[(((2 * w + 0) * 4 + ks) * 64 + lane) * 8];
            const bf16x8 b1 = *(const bf16x8*)&pWe2[(((2 * w + 1) * 4 + ks) * 64 + lane) * 8];
#pragma unroll
            for (int rt = 0; rt < 4; ++rt) {
                acc[rt][0] = __builtin_amdgcn_mfma_f32_16x16x32_bf16(a[rt], b0, acc[rt][0], 0, 0, 0);
                acc[rt][1] = __builtin_amdgcn_mfma_f32_16x16x32_bf16(a[rt], b1, acc[rt][1], 0, 0, 0);
            }
        }
    }
#pragma unroll
    for (int rt = 0; rt < 4; ++rt)
#pragma unroll
        for (int ctl = 0; ctl < 2; ++ctl)
#pragma unroll
            for (int j = 0; j < 4; ++j)
                acc[rt][ctl][j] = silu_f(acc[rt][ctl][j]);

    // ---- attention: att = sigmoid(sum_col m*Wa + ba) ----
    {
        float wac[2];
#pragma unroll
        for (int ctl = 0; ctl < 2; ++ctl)
            wac[ctl] = Wa[w * 32 + ctl * 16 + l15];
        float part[4][4];
#pragma unroll
        for (int rt = 0; rt < 4; ++rt)
#pragma unroll
            for (int j = 0; j < 4; ++j)
                part[rt][j] = fmaf(acc[rt][0][j], wac[0], acc[rt][1][j] * wac[1]);
#pragma unroll
        for (int msk = 1; msk < 16; msk <<= 1)
#pragma unroll
            for (int rt = 0; rt < 4; ++rt)
#pragma unroll
                for (int j = 0; j < 4; ++j)
                    part[rt][j] += __shfl_xor(part[rt][j], msk);
        if (l15 == 0) {
#pragma unroll
            for (int rt = 0; rt < 4; ++rt) {
                float4 p4 = make_float4(part[rt][0], part[rt][1], part[rt][2], part[rt][3]);
                *(float4*)&sWred[w][rt * 16 + g * 4] = p4;
            }
        }
    }
    __syncthreads();
    if (tid < TE) {
        const float s = sWred[0][tid] + sWred[1][tid] + sWred[2][tid] + sWred[3][tid];
        sAtt[tid] = sigmoid_f(s + ba[0]);
    }
    __syncthreads();

    // ---- phase 4: edge_feat = m*att -> ef view (bf16), no atomics ----
    char* const efb = sAb + 16384;
#pragma unroll
    for (int rt = 0; rt < 4; ++rt) {
        const float4 a4 = *(const float4*)&sAtt[rt * 16 + g * 4];
        const float at[4] = {a4.x, a4.y, a4.z, a4.w};
#pragma unroll
        for (int ctl = 0; ctl < 2; ++ctl) {
            const int col = w * 32 + ctl * 16 + l15;
#pragma unroll
            for (int j = 0; j < 4; ++j) {
                const float v = acc[rt][ctl][j] * at[j];
                const int row = rt * 16 + g * 4 + j;
                *(unsigned short*)(efb + row * 256 + ((col * 2) ^ ((row & 7) << 4))) = f2bf(v);
            }
        }
    }
    __syncthreads();

    // ---- phase 5: GEMMc  w = (silu(ef @ Wc1 + bc1)) @ Wc2 ----
    {
        float bc1c[2];
#pragma unroll
        for (int ctl = 0; ctl < 2; ++ctl)
            bc1c[ctl] = bc1[w * 32 + ctl * 16 + l15];
#pragma unroll
        for (int rt = 0; rt < 4; ++rt)
#pragma unroll
            for (int ctl = 0; ctl < 2; ++ctl)
#pragma unroll
                for (int j = 0; j < 4; ++j)
                    acc[rt][ctl][j] = bc1c[ctl];
        const unsigned short* pWc1 = pW + 49152;
#pragma unroll 1
        for (int ks = 0; ks < 4; ++ks) {
            bf16x8 a[4];
#pragma unroll
            for (int rt = 0; rt < 4; ++rt) {
                const int row = rt * 16 + l15;
                const int byc = g * 16 + ks * 64;
                a[rt] = *(const bf16x8*)(efb + row * 256 + (byc ^ ((row & 7) << 4)));
            }
            const bf16x8 b0 = *(const bf16x8*)&pWc1[(((2 * w + 0) * 4 + ks) * 64 + lane) * 8];
            const bf16x8 b1 = *(const bf16x8*)&pWc1[(((2 * w + 1) * 4 + ks) * 64 + lane) * 8];
#pragma unroll
            for (int rt = 0; rt < 4; ++rt) {
                acc[rt][0] = __builtin_amdgcn_mfma_f32_16x16x32_bf16(a[rt], b0, acc[rt][0], 0, 0, 0);
                acc[rt][1] = __builtin_amdgcn_mfma_f32_16x16x32_bf16(a[rt], b1, acc[rt][1], 0, 0, 0);
            }
        }
        float wcc[2];
#pragma unroll
        for (int ctl = 0; ctl < 2; ++ctl)
            wcc[ctl] = Wc2[w * 32 + ctl * 16 + l15];
        float part[4][4];
#pragma unroll
        for (int rt = 0; rt < 4; ++rt)
#pragma unroll
            for (int j = 0; j < 4; ++j)
                part[rt][j] = fmaf(silu_f(acc[rt][0][j]), wcc[0], silu_f(acc[rt][1][j]) * wcc[1]);
#pragma unroll
        for (int msk = 1; msk < 16; msk <<= 1)
#pragma unroll
            for (int rt = 0; rt < 4; ++rt)
#pragma unroll
                for (int j = 0; j < 4; ++j)
                    part[rt][j] += __shfl_xor(part[rt][j], msk);
        if (l15 == 0) {
#pragma unroll
            for (int rt = 0; rt < 4; ++rt) {
                float4 p4 = make_float4(part[rt][0], part[rt][1], part[rt][2], part[rt][3]);
                *(float4*)&sWred[w][rt * 16 + g * 4] = p4;
            }
        }
    }
    __syncthreads();

    // ---- phase 6a: agg_h segmented reduce over sorted rows ----
    {
        const int col  = tid & 127;
        const int half = tid >> 7;
        const int ebeg = half * 32;
        float a = 0.f;
        int cur = sRow[ebeg];
#pragma unroll 1
        for (int e = ebeg; e < ebeg + 32; ++e) {
            const int r = sRow[e];
            if (r != cur) {
                atomic_add_f(&agg_h[(size_t)cur * DD + col], a);
                a = 0.f; cur = r;
            }
            const unsigned short u =
                *(const unsigned short*)(efb + e * 256 + ((col * 2) ^ ((e & 7) << 4)));
            a += bf2f(u);
        }
        atomic_add_f(&agg_h[(size_t)cur * DD + col], a);
    }

    // ---- phase 6b: agg_c segmented reduce ----
    if (tid < 6) {
        const int c = tid % 3;
        const int half = tid / 3;
        const int ebeg = half * 32;
        float a = 0.f;
        int cur = sRow[ebeg];
#pragma unroll 1
        for (int e = ebeg; e < ebeg + 32; ++e) {
            const int r = sRow[e];
            if (r != cur) {
                atomic_add_f(&agg_c[cur * 3 + c], a);
                a = 0.f; cur = r;
            }
            const float wv = sWred[0][e] + sWred[1][e] + sWred[2][e] + sWred[3][e];
            a += sCd[e][c] * wv;
        }
        atomic_add_f(&agg_c[cur * 3 + c], a);
    }
}

// ---------------------------------------------------------------------------
// node kernel (fp32)
// ---------------------------------------------------------------------------
__device__ __forceinline__ void gemm_acc(const float (*S)[DD],
                                         const float* __restrict__ W,
                                         int el0, int c0, float acc[8][4])
{
#pragma unroll 1
    for (int k = 0; k < DD; k += 4) {
        const float4 w0 = *(const float4*)&W[(k + 0) * DD + c0];
        const float4 w1 = *(const float4*)&W[(k + 1) * DD + c0];
        const float4 w2 = *(const float4*)&W[(k + 2) * DD + c0];
        const float4 w3 = *(const float4*)&W[(k + 3) * DD + c0];
#pragma unroll
        for (int i = 0; i < 8; ++i) {
            const float4 x = *(const float4*)&S[el0 + i][k];
            acc[i][0] = fmaf(x.w, w3.x, fmaf(x.z, w2.x, fmaf(x.y, w1.x, fmaf(x.x, w0.x, acc[i][0]))));
            acc[i][1] = fmaf(x.w, w3.y, fmaf(x.z, w2.y, fmaf(x.y, w1.y, fmaf(x.x, w0.y, acc[i][1]))));
            acc[i][2] = fmaf(x.w, w3.z, fmaf(x.z, w2.z, fmaf(x.y, w1.z, fmaf(x.x, w0.z, acc[i][2]))));
            acc[i][3] = fmaf(x.w, w3.w, fmaf(x.z, w2.w, fmaf(x.y, w1.w, fmaf(x.x, w0.w, acc[i][3]))));
        }
    }
}

__global__ __launch_bounds__(256, 2)
void node_kernel(const float* __restrict__ h, const float* __restrict__ coord,
                 const float* __restrict__ Wn1, const float* __restrict__ bn1,
                 const float* __restrict__ Wn2, const float* __restrict__ bn2,
                 const float* __restrict__ agg_h, const float* __restrict__ agg_c,
                 const int* __restrict__ cnt,
                 float* __restrict__ hout, float* __restrict__ cout)
{
    __shared__ float sA[TE][DD];
    __shared__ float sB[TE][DD];

    const int tid = threadIdx.x;
    const int n0 = blockIdx.x * TE;

#pragma unroll 1
    for (int idx = tid; idx < TE * DD / 4; idx += 256) {
        const int e = idx / (DD / 4), k4 = (idx % (DD / 4)) * 4;
        const int n = n0 + e;
        float4 v = make_float4(0.f, 0.f, 0.f, 0.f);
        float4 u = make_float4(0.f, 0.f, 0.f, 0.f);
        if (n < NN) {
            v = *(const float4*)&h[(size_t)n * DD + k4];
            u = *(const float4*)&agg_h[(size_t)n * DD + k4];
        }
        *(float4*)&sA[e][k4] = v;
        *(float4*)&sB[e][k4] = u;
    }
    __syncthreads();

    const int cg = tid & 31, eg = tid >> 5;
    const int c0 = cg * 4, el0 = eg * 8;

    float acc[8][4];
    {
        const float4 b = *(const float4*)&bn1[c0];
#pragma unroll
        for (int i = 0; i < 8; ++i) { acc[i][0] = b.x; acc[i][1] = b.y; acc[i][2] = b.z; acc[i][3] = b.w; }
    }
    gemm_acc(sA, Wn1, el0, c0, acc);
    gemm_acc(sB, Wn1 + 128 * DD, el0, c0, acc);
    __syncthreads();
#pragma unroll
    for (int i = 0; i < 8; ++i) {
        sA[el0 + i][c0 + 0] = silu_f(acc[i][0]);
        sA[el0 + i][c0 + 1] = silu_f(acc[i][1]);
        sA[el0 + i][c0 + 2] = silu_f(acc[i][2]);
        sA[el0 + i][c0 + 3] = silu_f(acc[i][3]);
    }
    __syncthreads();

    float o[8][4];
    {
        const float4 b = *(const float4*)&bn2[c0];
#pragma unroll
        for (int i = 0; i < 8; ++i) { o[i][0] = b.x; o[i][1] = b.y; o[i][2] = b.z; o[i][3] = b.w; }
    }
    gemm_acc(sA, Wn2, el0, c0, o);
#pragma unroll
    for (int i = 0; i < 8; ++i) {
        const int n = n0 + el0 + i;
        if (n < NN) {
            const float4 hv = *(const float4*)&h[(size_t)n * DD + c0];
            float4 r;
            r.x = hv.x + o[i][0]; r.y = hv.y + o[i][1];
            r.z = hv.z + o[i][2]; r.w = hv.w + o[i][3];
            *(float4*)&hout[(size_t)n * DD + c0] = r;
        }
    }

    if (tid < TE * 3) {
        const int e = tid / 3, c = tid % 3;
        const int n = n0 + e;
        if (n < NN) {
            const float cn = fmaxf((float)cnt[n], 1.0f);
            cout[n * 3 + c] = coord[n * 3 + c] + agg_c[n * 3 + c] / cn;
        }
    }
}

extern "C" void kernel_launch(void* const* d_in, const int* in_sizes, int n_in,
                              void* d_out, int out_size, void* d_ws, size_t ws_size,
                              hipStream_t stream)
{
    const float* h     = (const float*)d_in[0];
    const int*   ei    = (const int*)  d_in[1];
    const float* coord = (const float*)d_in[2];
    const float* We1   = (const float*)d_in[3];
    const float* be1   = (const float*)d_in[4];
    const float* We2   = (const float*)d_in[5];
    const float* be2   = (const float*)d_in[6];
    const float* Wa    = (const float*)d_in[7];
    const float* ba    = (const float*)d_in[8];
    const float* Wn1   = (const float*)d_in[9];
    const float* bn1   = (const float*)d_in[10];
    const float* Wn2   = (const float*)d_in[11];
    const float* bn2   = (const float*)d_in[12];
    const float* Wc1   = (const float*)d_in[13];
    const float* bc1   = (const float*)d_in[14];
    const float* Wc2   = (const float*)d_in[15];

    // ws layout (16B-aligned chunks)
    float* agg_h   = (float*)d_ws;                   // N*D           = 1,280,000 f
    float* agg_c   = agg_h + (size_t)NN * DD;        // N*3           =    30,000 f
    int*   cnt_i   = (int*)(agg_c + (size_t)NN * 3); // N             =    10,000 i
    int*   tmp_i   = cnt_i + NN;                     // N             =    10,000 i
    int*   offs    = tmp_i + NN;                     // N+1 (pad to 10004)
    int*   perm    = offs + 10004;                   // E             =   320,000 i
    unsigned short* pW = (unsigned short*)(perm + EE);  // 65536 bf16

    // zero agg_h, agg_c, cnt_i, tmp_i
    (void)hipMemsetAsync(d_ws, 0, (size_t)(NN * DD + NN * 3 + NN + NN) * sizeof(float), stream);

    hist_kernel<<<(EE + 255) / 256, 256, 0, stream>>>(ei, cnt_i);
    scan_kernel<<<1, 512, 0, stream>>>(cnt_i, offs);
    scatter_kernel<<<(EE + 255) / 256, 256, 0, stream>>>(ei, offs, tmp_i, perm);
    prep_kernel<<<256, 256, 0, stream>>>(We1, We2, Wc1, pW);

    edge_kernel<<<EE / TE, 256, 0, stream>>>(h, ei, coord, perm, We1, be1, be2,
                                             Wa, ba, bc1, Wc2, pW, agg_h, agg_c);

    float* hout = (float*)d_out;
    float* cout = hout + (size_t)NN * DD;
    node_kernel<<<(NN + TE - 1) / TE, 256, 0, stream>>>(h, coord, Wn1, bn1, Wn2, bn2,
                                                        agg_h, agg_c, cnt_i, hout, cout);
}

// Round 4
// 258.368 us; speedup vs baseline: 1.1606x; 1.1606x over previous
//
#include <hip/hip_runtime.h>
#include <hip/hip_bf16.h>

#define NN 10000
#define EE 320000
#define DD 128
#define TEE 128  // edges per block (edge kernel)
#define TN 64    // nodes per block (node kernel)

typedef __attribute__((ext_vector_type(8))) __bf16 bf16x8;
typedef __attribute__((ext_vector_type(2))) __bf16 bf16x2;
typedef __attribute__((ext_vector_type(4))) float  f32x4;

__device__ __forceinline__ float silu_f(float x) {
    return x / (1.0f + __expf(-x));
}
__device__ __forceinline__ float sigmoid_f(float x) {
    return 1.0f / (1.0f + __expf(-x));
}

// native conversions: compiler emits v_cvt_pk_bf16_f32 for pairs
__device__ __forceinline__ unsigned pkbf(float a, float b) {
    bf16x2 v; v.x = (__bf16)a; v.y = (__bf16)b;
    return __builtin_bit_cast(unsigned, v);
}
__device__ __forceinline__ unsigned short sbf(float a) {
    return __builtin_bit_cast(unsigned short, (__bf16)a);
}
__device__ __forceinline__ float bf2f(unsigned short u) {
    return __builtin_bit_cast(float, (unsigned)u << 16);
}

__device__ __forceinline__ float atomic_add_f(float* p, float v) {
    return unsafeAtomicAdd(p, v);
}

// ---------------------------------------------------------------------------
// CSR build: histogram -> scan -> scatter (row-sorted edge permutation)
// ---------------------------------------------------------------------------
__global__ void hist_kernel(const int* __restrict__ ei, int* __restrict__ cnt)
{
    const int e = blockIdx.x * 256 + threadIdx.x;
    if (e < EE) atomicAdd(&cnt[ei[e]], 1);
}

__global__ __launch_bounds__(512)
void scan_kernel(const int* __restrict__ cnt, int* __restrict__ offs)
{
    __shared__ int part[512];
    const int t = threadIdx.x;
    const int base = t * 20;
    int loc[20];
    int s = 0;
#pragma unroll
    for (int i = 0; i < 20; ++i) {
        const int idx = base + i;
        const int v = (idx < NN) ? cnt[idx] : 0;
        loc[i] = s; s += v;
    }
    part[t] = s;
    __syncthreads();
    for (int d = 1; d < 512; d <<= 1) {
        const int v = (t >= d) ? part[t - d] : 0;
        __syncthreads();
        part[t] += v;
        __syncthreads();
    }
    const int pre = (t == 0) ? 0 : part[t - 1];
#pragma unroll
    for (int i = 0; i < 20; ++i) {
        const int idx = base + i;
        if (idx < NN) offs[idx] = pre + loc[i];
    }
    if (t == 511) offs[NN] = pre + s;   // == EE
}

__global__ void scatter_kernel(const int* __restrict__ ei, const int* __restrict__ offs,
                               int* __restrict__ tmp, int* __restrict__ perm)
{
    const int e = blockIdx.x * 256 + threadIdx.x;
    if (e >= EE) return;
    const int r = ei[e];
    const int pos = offs[r] + atomicAdd(&tmp[r], 1);
    perm[pos] = e;
}

// ---------------------------------------------------------------------------
// prep: convert + pack weights into per-lane MFMA B-fragments (bf16).
// Fragment (ct, ks): lane l holds B[k][n], n = ct*16+(l&15), k = ks*32+(l>>4)*8+j.
// Regions (element offsets): We1 @0 (nks=8), We2 @32768 (4), Wc1 @49152 (4),
//                            Wn1 @65536 (8), Wn2 @98304 (4). Total 114688.
// ---------------------------------------------------------------------------
__global__ void prep_kernel(const float* __restrict__ We1,
                            const float* __restrict__ We2,
                            const float* __restrict__ Wc1,
                            const float* __restrict__ Wn1,
                            const float* __restrict__ Wn2,
                            unsigned short* __restrict__ pW)
{
    const int idx = blockIdx.x * 256 + threadIdx.x;
    const float* src; int loc, nks;
    if (idx < 32768)       { src = We1; loc = idx;         nks = 8; }
    else if (idx < 49152)  { src = We2; loc = idx - 32768; nks = 4; }
    else if (idx < 65536)  { src = Wc1; loc = idx - 49152; nks = 4; }
    else if (idx < 98304)  { src = Wn1; loc = idx - 65536; nks = 8; }
    else                   { src = Wn2; loc = idx - 98304; nks = 4; }
    const int per_ct = nks * 512;
    const int ct = loc / per_ct;
    const int r  = loc % per_ct;
    const int ks = r >> 9;
    const int r2 = r & 511;
    const int ln = r2 >> 3;
    const int j  = r2 & 7;
    const int k  = ks * 32 + (ln >> 4) * 8 + j;
    const int n  = ct * 16 + (ln & 15);
    pW[idx] = sbf(src[k * DD + n]);
}

// ---------------------------------------------------------------------------
// edge kernel: 128 row-sorted edges/block, 8 waves (512 thr), MFMA 16x16x32.
// Wave w: row-half rh=w>>2 (64 rows), col-quarter cq=w&3 (32 cols).
// ---------------------------------------------------------------------------
__global__ __launch_bounds__(512, 4)
void edge_kernel(const float* __restrict__ h, const int* __restrict__ ei,
                 const float* __restrict__ coord, const int* __restrict__ perm,
                 const float* __restrict__ We1, const float* __restrict__ be1,
                 const float* __restrict__ be2,
                 const float* __restrict__ Wa, const float* __restrict__ ba,
                 const float* __restrict__ bc1, const float* __restrict__ Wc2,
                 const unsigned short* __restrict__ pW,
                 float* __restrict__ agg_h, float* __restrict__ agg_c)
{
    // A buffer 64KB: GEMM1 view [128][512B]; m1 view bytes [0,32768) ([128][256B]);
    // ef view bytes [32768,65536)
    __shared__ __align__(16) unsigned short sAbuf[128 * 256];
    __shared__ __align__(16) float sWred[4][128];
    __shared__ __align__(16) int   sRow[128];
    __shared__ int   sCol[128];
    __shared__ __align__(16) float sRad[128];
    __shared__ __align__(16) float sAtt[128];
    __shared__ float sCd[128][3];

    const int tid  = threadIdx.x;
    const int w    = tid >> 6;
    const int lane = tid & 63;
    const int g    = lane >> 4;
    const int l15  = lane & 15;
    const int rh   = w >> 2;          // row half (0/1)
    const int cq   = w & 3;           // col quarter
    const int rb   = rh * 64;         // row base
    const int e0g  = blockIdx.x * TEE;

    char* const sAb = (char*)sAbuf;

    // ---- phase 0: permuted indices, coord diff, radial ----
    if (tid < TEE) {
        const int e = perm[e0g + tid];
        const int r = ei[e];
        const int c = ei[EE + e];
        sRow[tid] = r; sCol[tid] = c;
        const float dx = coord[r * 3 + 0] - coord[c * 3 + 0];
        const float dy = coord[r * 3 + 1] - coord[c * 3 + 1];
        const float dz = coord[r * 3 + 2] - coord[c * 3 + 2];
        sCd[tid][0] = dx; sCd[tid][1] = dy; sCd[tid][2] = dz;
        sRad[tid] = dx * dx + dy * dy + dz * dz;
    }
    __syncthreads();

    // ---- phase 1: stage [h[row] | h[col]] bf16 into swizzled A-tile ----
    {
        const int halfsel = (lane >= 32) ? 1 : 0;
        const int bytec   = (lane & 31) * 8 + halfsel * 256;
#pragma unroll 4
        for (int s = 0; s < 16; ++s) {
            const int e = w * 16 + s;
            const int r = halfsel ? sCol[e] : sRow[e];
            const float4 v = *(const float4*)&h[(size_t)r * DD + (lane & 31) * 4];
            uint2 pk;
            pk.x = pkbf(v.x, v.y);
            pk.y = pkbf(v.z, v.w);
            *(uint2*)(sAb + e * 512 + (bytec ^ ((e & 7) << 4))) = pk;
        }
    }
    __syncthreads();

    f32x4 acc[4][2];

    // ---- phase 2: GEMM1  m1 = silu(A @ We1 + radial*wr + be1) ----
    {
        float be1c[2], wrc[2];
#pragma unroll
        for (int ctl = 0; ctl < 2; ++ctl) {
            const int col = cq * 32 + ctl * 16 + l15;
            be1c[ctl] = be1[col];
            wrc[ctl]  = We1[256 * DD + col];
        }
#pragma unroll
        for (int rt = 0; rt < 4; ++rt) {
            const float4 rad4 = *(const float4*)&sRad[rb + rt * 16 + g * 4];
            const float rr[4] = {rad4.x, rad4.y, rad4.z, rad4.w};
#pragma unroll
            for (int ctl = 0; ctl < 2; ++ctl)
#pragma unroll
                for (int j = 0; j < 4; ++j)
                    acc[rt][ctl][j] = fmaf(rr[j], wrc[ctl], be1c[ctl]);
        }
#pragma unroll 1
        for (int ks = 0; ks < 8; ++ks) {
            bf16x8 a[4];
#pragma unroll
            for (int rt = 0; rt < 4; ++rt) {
                const int row = rb + rt * 16 + l15;
                const int byc = g * 16 + ks * 64;
                a[rt] = *(const bf16x8*)(sAb + row * 512 + (byc ^ ((row & 7) << 4)));
            }
            const bf16x8 b0 = *(const bf16x8*)&pW[(((2 * cq + 0) * 8 + ks) * 64 + lane) * 8];
            const bf16x8 b1 = *(const bf16x8*)&pW[(((2 * cq + 1) * 8 + ks) * 64 + lane) * 8];
#pragma unroll
            for (int rt = 0; rt < 4; ++rt) {
                acc[rt][0] = __builtin_amdgcn_mfma_f32_16x16x32_bf16(a[rt], b0, acc[rt][0], 0, 0, 0);
                acc[rt][1] = __builtin_amdgcn_mfma_f32_16x16x32_bf16(a[rt], b1, acc[rt][1], 0, 0, 0);
            }
        }
    }
    __syncthreads();

    // silu -> bf16 -> m1 view (256 B rows, same XOR swizzle)
#pragma unroll
    for (int rt = 0; rt < 4; ++rt)
#pragma unroll
        for (int ctl = 0; ctl < 2; ++ctl)
#pragma unroll
            for (int j = 0; j < 4; ++j) {
                const int row = rb + rt * 16 + g * 4 + j;
                const int col = cq * 32 + ctl * 16 + l15;
                *(unsigned short*)(sAb + row * 256 + ((col * 2) ^ ((row & 7) << 4)))
                    = sbf(silu_f(acc[rt][ctl][j]));
            }
    __syncthreads();

    // ---- phase 3: GEMM2  m = silu(m1 @ We2 + be2) ----
    {
        float be2c[2];
#pragma unroll
        for (int ctl = 0; ctl < 2; ++ctl)
            be2c[ctl] = be2[cq * 32 + ctl * 16 + l15];
#pragma unroll
        for (int rt = 0; rt < 4; ++rt)
#pragma unroll
            for (int ctl = 0; ctl < 2; ++ctl)
#pragma unroll
                for (int j = 0; j < 4; ++j)
                    acc[rt][ctl][j] = be2c[ctl];
        const unsigned short* pWe2 = pW + 32768;
#pragma unroll 1
        for (int ks = 0; ks < 4; ++ks) {
            bf16x8 a[4];
#pragma unroll
            for (int rt = 0; rt < 4; ++rt) {
                const int row = rb + rt * 16 + l15;
                const int byc = g * 16 + ks * 64;
                a[rt] = *(const bf16x8*)(sAb + row * 256 + (byc ^ ((row & 7) << 4)));
            }
            const bf16x8 b0 = *(const bf16x8*)&pWe2[(((2 * cq + 0) * 4 + ks) * 64 + lane) * 8];
            const bf16x8 b1 = *(const bf16x8*)&pWe2[(((2 * cq + 1) * 4 + ks) * 64 + lane) * 8];
#pragma unroll
            for (int rt = 0; rt < 4; ++rt) {
                acc[rt][0] = __builtin_amdgcn_mfma_f32_16x16x32_bf16(a[rt], b0, acc[rt][0], 0, 0, 0);
                acc[rt][1] = __builtin_amdgcn_mfma_f32_16x16x32_bf16(a[rt], b1, acc[rt][1], 0, 0, 0);
            }
        }
    }
#pragma unroll
    for (int rt = 0; rt < 4; ++rt)
#pragma unroll
        for (int ctl = 0; ctl < 2; ++ctl)
#pragma unroll
            for (int j = 0; j < 4; ++j)
                acc[rt][ctl][j] = silu_f(acc[rt][ctl][j]);

    // ---- attention: att = sigmoid(sum_col m*Wa + ba) ----
    {
        float wac[2];
#pragma unroll
        for (int ctl = 0; ctl < 2; ++ctl)
            wac[ctl] = Wa[cq * 32 + ctl * 16 + l15];
        float part[4][4];
#pragma unroll
        for (int rt = 0; rt < 4; ++rt)
#pragma unroll
            for (int j = 0; j < 4; ++j)
                part[rt][j] = fmaf(acc[rt][0][j], wac[0], acc[rt][1][j] * wac[1]);
#pragma unroll
        for (int msk = 1; msk < 16; msk <<= 1)
#pragma unroll
            for (int rt = 0; rt < 4; ++rt)
#pragma unroll
                for (int j = 0; j < 4; ++j)
                    part[rt][j] += __shfl_xor(part[rt][j], msk);
        if (l15 == 0) {
#pragma unroll
            for (int rt = 0; rt < 4; ++rt) {
                float4 p4 = make_float4(part[rt][0], part[rt][1], part[rt][2], part[rt][3]);
                *(float4*)&sWred[cq][rb + rt * 16 + g * 4] = p4;
            }
        }
    }
    __syncthreads();
    if (tid < TEE) {
        const float s = sWred[0][tid] + sWred[1][tid] + sWred[2][tid] + sWred[3][tid];
        sAtt[tid] = sigmoid_f(s + ba[0]);
    }
    __syncthreads();

    // ---- phase 4: edge_feat = m*att -> ef view (bf16) ----
    char* const efb = sAb + 32768;
#pragma unroll
    for (int rt = 0; rt < 4; ++rt) {
        const float4 a4 = *(const float4*)&sAtt[rb + rt * 16 + g * 4];
        const float at[4] = {a4.x, a4.y, a4.z, a4.w};
#pragma unroll
        for (int ctl = 0; ctl < 2; ++ctl) {
            const int col = cq * 32 + ctl * 16 + l15;
#pragma unroll
            for (int j = 0; j < 4; ++j) {
                const float v = acc[rt][ctl][j] * at[j];
                const int row = rb + rt * 16 + g * 4 + j;
                *(unsigned short*)(efb + row * 256 + ((col * 2) ^ ((row & 7) << 4))) = sbf(v);
            }
        }
    }
    __syncthreads();

    // ---- phase 5: GEMMc  w = (silu(ef @ Wc1 + bc1)) @ Wc2 ----
    {
        float bc1c[2];
#pragma unroll
        for (int ctl = 0; ctl < 2; ++ctl)
            bc1c[ctl] = bc1[cq * 32 + ctl * 16 + l15];
#pragma unroll
        for (int rt = 0; rt < 4; ++rt)
#pragma unroll
            for (int ctl = 0; ctl < 2; ++ctl)
#pragma unroll
                for (int j = 0; j < 4; ++j)
                    acc[rt][ctl][j] = bc1c[ctl];
        const unsigned short* pWc1 = pW + 49152;
#pragma unroll 1
        for (int ks = 0; ks < 4; ++ks) {
            bf16x8 a[4];
#pragma unroll
            for (int rt = 0; rt < 4; ++rt) {
                const int row = rb + rt * 16 + l15;
                const int byc = g * 16 + ks * 64;
                a[rt] = *(const bf16x8*)(efb + row * 256 + (byc ^ ((row & 7) << 4)));
            }
            const bf16x8 b0 = *(const bf16x8*)&pWc1[(((2 * cq + 0) * 4 + ks) * 64 + lane) * 8];
            const bf16x8 b1 = *(const bf16x8*)&pWc1[(((2 * cq + 1) * 4 + ks) * 64 + lane) * 8];
#pragma unroll
            for (int rt = 0; rt < 4; ++rt) {
                acc[rt][0] = __builtin_amdgcn_mfma_f32_16x16x32_bf16(a[rt], b0, acc[rt][0], 0, 0, 0);
                acc[rt][1] = __builtin_amdgcn_mfma_f32_16x16x32_bf16(a[rt], b1, acc[rt][1], 0, 0, 0);
            }
        }
        float wcc[2];
#pragma unroll
        for (int ctl = 0; ctl < 2; ++ctl)
            wcc[ctl] = Wc2[cq * 32 + ctl * 16 + l15];
        float part[4][4];
#pragma unroll
        for (int rt = 0; rt < 4; ++rt)
#pragma unroll
            for (int j = 0; j < 4; ++j)
                part[rt][j] = fmaf(silu_f(acc[rt][0][j]), wcc[0], silu_f(acc[rt][1][j]) * wcc[1]);
#pragma unroll
        for (int msk = 1; msk < 16; msk <<= 1)
#pragma unroll
            for (int rt = 0; rt < 4; ++rt)
#pragma unroll
                for (int j = 0; j < 4; ++j)
                    part[rt][j] += __shfl_xor(part[rt][j], msk);
        if (l15 == 0) {
#pragma unroll
            for (int rt = 0; rt < 4; ++rt) {
                float4 p4 = make_float4(part[rt][0], part[rt][1], part[rt][2], part[rt][3]);
                *(float4*)&sWred[cq][rb + rt * 16 + g * 4] = p4;
            }
        }
    }
    __syncthreads();

    // ---- phase 6a: agg_h segmented reduce over sorted rows ----
    {
        const int col = tid & 127;
        const int seg = tid >> 7;           // 4 segments of 32 edges
        const int ebeg = seg * 32;
        float a = 0.f;
        int cur = sRow[ebeg];
#pragma unroll 1
        for (int e = ebeg; e < ebeg + 32; ++e) {
            const int r = sRow[e];
            if (r != cur) {
                atomic_add_f(&agg_h[(size_t)cur * DD + col], a);
                a = 0.f; cur = r;
            }
            const unsigned short u =
                *(const unsigned short*)(efb + e * 256 + ((col * 2) ^ ((e & 7) << 4)));
            a += bf2f(u);
        }
        atomic_add_f(&agg_h[(size_t)cur * DD + col], a);
    }

    // ---- phase 6b: agg_c segmented reduce ----
    if (tid < 12) {
        const int c = tid % 3;
        const int seg = tid / 3;
        const int ebeg = seg * 32;
        float a = 0.f;
        int cur = sRow[ebeg];
#pragma unroll 1
        for (int e = ebeg; e < ebeg + 32; ++e) {
            const int r = sRow[e];
            if (r != cur) {
                atomic_add_f(&agg_c[cur * 3 + c], a);
                a = 0.f; cur = r;
            }
            const float wv = sWred[0][e] + sWred[1][e] + sWred[2][e] + sWred[3][e];
            a += sCd[e][c] * wv;
        }
        atomic_add_f(&agg_c[cur * 3 + c], a);
    }
}

// ---------------------------------------------------------------------------
// node kernel: 64 nodes/block, 4 waves, MFMA. [h | agg_h] @ Wn1 -> silu
// -> @ Wn2 + bn2 + h (residual). Coord out fused.
// ---------------------------------------------------------------------------
__global__ __launch_bounds__(256, 2)
void node_kernel(const float* __restrict__ h, const float* __restrict__ coord,
                 const float* __restrict__ bn1, const float* __restrict__ bn2,
                 const unsigned short* __restrict__ pW,
                 const float* __restrict__ agg_h, const float* __restrict__ agg_c,
                 const int* __restrict__ cnt,
                 float* __restrict__ hout, float* __restrict__ cout)
{
    __shared__ __align__(16) unsigned short sAbuf[64 * 256];   // 32KB

    const int tid  = threadIdx.x;
    const int w    = tid >> 6;
    const int lane = tid & 63;
    const int g    = lane >> 4;
    const int l15  = lane & 15;
    const int n0   = blockIdx.x * TN;
    char* const sAb = (char*)sAbuf;

    // ---- stage [h | agg_h] bf16, swizzled ----
    {
        const int halfsel = (lane >= 32) ? 1 : 0;
        const int bytec   = (lane & 31) * 8 + halfsel * 256;
        const float* src  = halfsel ? agg_h : h;
#pragma unroll 4
        for (int s = 0; s < 16; ++s) {
            const int row = w * 16 + s;
            const int n = n0 + row;
            float4 v = make_float4(0.f, 0.f, 0.f, 0.f);
            if (n < NN) v = *(const float4*)&src[(size_t)n * DD + (lane & 31) * 4];
            uint2 pk;
            pk.x = pkbf(v.x, v.y);
            pk.y = pkbf(v.z, v.w);
            *(uint2*)(sAb + row * 512 + (bytec ^ ((row & 7) << 4))) = pk;
        }
    }
    __syncthreads();

    f32x4 acc[4][2];

    // ---- GEMM1: silu([h|agg] @ Wn1 + bn1) ----
    {
        float bc[2];
#pragma unroll
        for (int ctl = 0; ctl < 2; ++ctl)
            bc[ctl] = bn1[w * 32 + ctl * 16 + l15];
#pragma unroll
        for (int rt = 0; rt < 4; ++rt)
#pragma unroll
            for (int ctl = 0; ctl < 2; ++ctl)
#pragma unroll
                for (int j = 0; j < 4; ++j)
                    acc[rt][ctl][j] = bc[ctl];
        const unsigned short* pWn1 = pW + 65536;
#pragma unroll 1
        for (int ks = 0; ks < 8; ++ks) {
            bf16x8 a[4];
#pragma unroll
            for (int rt = 0; rt < 4; ++rt) {
                const int row = rt * 16 + l15;
                const int byc = g * 16 + ks * 64;
                a[rt] = *(const bf16x8*)(sAb + row * 512 + (byc ^ ((row & 7) << 4)));
            }
            const bf16x8 b0 = *(const bf16x8*)&pWn1[(((2 * w + 0) * 8 + ks) * 64 + lane) * 8];
            const bf16x8 b1 = *(const bf16x8*)&pWn1[(((2 * w + 1) * 8 + ks) * 64 + lane) * 8];
#pragma unroll
            for (int rt = 0; rt < 4; ++rt) {
                acc[rt][0] = __builtin_amdgcn_mfma_f32_16x16x32_bf16(a[rt], b0, acc[rt][0], 0, 0, 0);
                acc[rt][1] = __builtin_amdgcn_mfma_f32_16x16x32_bf16(a[rt], b1, acc[rt][1], 0, 0, 0);
            }
        }
    }
    __syncthreads();
#pragma unroll
    for (int rt = 0; rt < 4; ++rt)
#pragma unroll
        for (int ctl = 0; ctl < 2; ++ctl)
#pragma unroll
            for (int j = 0; j < 4; ++j) {
                const int row = rt * 16 + g * 4 + j;
                const int col = w * 32 + ctl * 16 + l15;
                *(unsigned short*)(sAb + row * 256 + ((col * 2) ^ ((row & 7) << 4)))
                    = sbf(silu_f(acc[rt][ctl][j]));
            }
    __syncthreads();

    // ---- GEMM2 + bias + residual ----
    {
        float bc[2];
#pragma unroll
        for (int ctl = 0; ctl < 2; ++ctl)
            bc[ctl] = bn2[w * 32 + ctl * 16 + l15];
#pragma unroll
        for (int rt = 0; rt < 4; ++rt)
#pragma unroll
            for (int ctl = 0; ctl < 2; ++ctl)
#pragma unroll
                for (int j = 0; j < 4; ++j)
                    acc[rt][ctl][j] = bc[ctl];
        const unsigned short* pWn2 = pW + 98304;
#pragma unroll 1
        for (int ks = 0; ks < 4; ++ks) {
            bf16x8 a[4];
#pragma unroll
            for (int rt = 0; rt < 4; ++rt) {
                const int row = rt * 16 + l15;
                const int byc = g * 16 + ks * 64;
                a[rt] = *(const bf16x8*)(sAb + row * 256 + (byc ^ ((row & 7) << 4)));
            }
            const bf16x8 b0 = *(const bf16x8*)&pWn2[(((2 * w + 0) * 4 + ks) * 64 + lane) * 8];
            const bf16x8 b1 = *(const bf16x8*)&pWn2[(((2 * w + 1) * 4 + ks) * 64 + lane) * 8];
#pragma unroll
            for (int rt = 0; rt < 4; ++rt) {
                acc[rt][0] = __builtin_amdgcn_mfma_f32_16x16x32_bf16(a[rt], b0, acc[rt][0], 0, 0, 0);
                acc[rt][1] = __builtin_amdgcn_mfma_f32_16x16x32_bf16(a[rt], b1, acc[rt][1], 0, 0, 0);
            }
        }
    }
#pragma unroll
    for (int rt = 0; rt < 4; ++rt)
#pragma unroll
        for (int ctl = 0; ctl < 2; ++ctl)
#pragma unroll
            for (int j = 0; j < 4; ++j) {
                const int row = rt * 16 + g * 4 + j;
                const int n = n0 + row;
                if (n < NN) {
                    const int col = w * 32 + ctl * 16 + l15;
                    hout[(size_t)n * DD + col] = h[(size_t)n * DD + col] + acc[rt][ctl][j];
                }
            }

    // ---- coord out ----
    if (tid < TN * 3) {
        const int e = tid / 3, c = tid % 3;
        const int n = n0 + e;
        if (n < NN) {
            const float cn = fmaxf((float)cnt[n], 1.0f);
            cout[n * 3 + c] = coord[n * 3 + c] + agg_c[n * 3 + c] / cn;
        }
    }
}

extern "C" void kernel_launch(void* const* d_in, const int* in_sizes, int n_in,
                              void* d_out, int out_size, void* d_ws, size_t ws_size,
                              hipStream_t stream)
{
    const float* h     = (const float*)d_in[0];
    const int*   ei    = (const int*)  d_in[1];
    const float* coord = (const float*)d_in[2];
    const float* We1   = (const float*)d_in[3];
    const float* be1   = (const float*)d_in[4];
    const float* We2   = (const float*)d_in[5];
    const float* be2   = (const float*)d_in[6];
    const float* Wa    = (const float*)d_in[7];
    const float* ba    = (const float*)d_in[8];
    const float* Wn1   = (const float*)d_in[9];
    const float* bn1   = (const float*)d_in[10];
    const float* Wn2   = (const float*)d_in[11];
    const float* bn2   = (const float*)d_in[12];
    const float* Wc1   = (const float*)d_in[13];
    const float* bc1   = (const float*)d_in[14];
    const float* Wc2   = (const float*)d_in[15];

    // ws layout
    float* agg_h   = (float*)d_ws;                   // N*D
    float* agg_c   = agg_h + (size_t)NN * DD;        // N*3
    int*   cnt_i   = (int*)(agg_c + (size_t)NN * 3); // N
    int*   tmp_i   = cnt_i + NN;                     // N
    int*   offs    = tmp_i + NN;                     // N+1 (pad 10004)
    int*   perm    = offs + 10004;                   // E
    unsigned short* pW = (unsigned short*)(perm + EE);  // 114688 bf16

    (void)hipMemsetAsync(d_ws, 0, (size_t)(NN * DD + NN * 3 + NN + NN) * sizeof(float), stream);

    hist_kernel<<<(EE + 255) / 256, 256, 0, stream>>>(ei, cnt_i);
    scan_kernel<<<1, 512, 0, stream>>>(cnt_i, offs);
    scatter_kernel<<<(EE + 255) / 256, 256, 0, stream>>>(ei, offs, tmp_i, perm);
    prep_kernel<<<448, 256, 0, stream>>>(We1, We2, Wc1, Wn1, Wn2, pW);

    edge_kernel<<<EE / TEE, 512, 0, stream>>>(h, ei, coord, perm, We1, be1, be2,
                                              Wa, ba, bc1, Wc2, pW, agg_h, agg_c);

    float* hout = (float*)d_out;
    float* cout = hout + (size_t)NN * DD;
    node_kernel<<<(NN + TN - 1) / TN, 256, 0, stream>>>(h, coord, bn1, bn2, pW,
                                                        agg_h, agg_c, cnt_i, hout, cout);
}

// Round 5
// 218.209 us; speedup vs baseline: 1.3742x; 1.1840x over previous
//
#include <hip/hip_runtime.h>
#include <hip/hip_bf16.h>

#define NN 10000
#define EE 320000
#define DD 128
#define TEE 128  // edges per block (edge kernel)
#define TN 64    // nodes per block (node/pq kernels)

typedef __attribute__((ext_vector_type(8))) __bf16 bf16x8;
typedef __attribute__((ext_vector_type(2))) __bf16 bf16x2;
typedef __attribute__((ext_vector_type(8))) unsigned short ushort8;
typedef __attribute__((ext_vector_type(4))) float  f32x4;

__device__ __forceinline__ float silu_f(float x) {
    return x / (1.0f + __expf(-x));
}
__device__ __forceinline__ float sigmoid_f(float x) {
    return 1.0f / (1.0f + __expf(-x));
}

// native conversions: compiler emits v_cvt_pk_bf16_f32 for pairs
__device__ __forceinline__ unsigned pkbf(float a, float b) {
    bf16x2 v; v.x = (__bf16)a; v.y = (__bf16)b;
    return __builtin_bit_cast(unsigned, v);
}
__device__ __forceinline__ unsigned short sbf(float a) {
    return __builtin_bit_cast(unsigned short, (__bf16)a);
}
__device__ __forceinline__ float bf2f(unsigned short u) {
    return __builtin_bit_cast(float, (unsigned)u << 16);
}

__device__ __forceinline__ float atomic_add_f(float* p, float v) {
    return unsafeAtomicAdd(p, v);
}

// ---------------------------------------------------------------------------
// CSR build: histogram -> scan -> scatter (row-sorted edge permutation)
// ---------------------------------------------------------------------------
__global__ void hist_kernel(const int* __restrict__ ei, int* __restrict__ cnt)
{
    const int e = blockIdx.x * 256 + threadIdx.x;
    if (e < EE) atomicAdd(&cnt[ei[e]], 1);
}

__global__ __launch_bounds__(512)
void scan_kernel(const int* __restrict__ cnt, int* __restrict__ offs)
{
    __shared__ int part[512];
    const int t = threadIdx.x;
    const int base = t * 20;
    int loc[20];
    int s = 0;
#pragma unroll
    for (int i = 0; i < 20; ++i) {
        const int idx = base + i;
        const int v = (idx < NN) ? cnt[idx] : 0;
        loc[i] = s; s += v;
    }
    part[t] = s;
    __syncthreads();
    for (int d = 1; d < 512; d <<= 1) {
        const int v = (t >= d) ? part[t - d] : 0;
        __syncthreads();
        part[t] += v;
        __syncthreads();
    }
    const int pre = (t == 0) ? 0 : part[t - 1];
#pragma unroll
    for (int i = 0; i < 20; ++i) {
        const int idx = base + i;
        if (idx < NN) offs[idx] = pre + loc[i];
    }
    if (t == 511) offs[NN] = pre + s;   // == EE
}

__global__ void scatter_kernel(const int* __restrict__ ei, const int* __restrict__ offs,
                               int* __restrict__ tmp, int* __restrict__ perm)
{
    const int e = blockIdx.x * 256 + threadIdx.x;
    if (e >= EE) return;
    const int r = ei[e];
    const int pos = offs[r] + atomicAdd(&tmp[r], 1);
    perm[pos] = e;
}

// ---------------------------------------------------------------------------
// prep: convert + pack weights into per-lane MFMA B-fragments (bf16).
// Fragment (ct, ks): lane l holds B[k][n], n = ct*16+(l&15), k = ks*32+(l>>4)*8+j.
// Regions (element offsets):
//   We1a (rows 0..127)   @0      nks=4
//   We1b (rows 128..255) @16384  nks=4
//   We2                  @32768  nks=4
//   Wc1                  @49152  nks=4
//   Wn1 (256 rows)       @65536  nks=8
//   Wn2                  @98304  nks=4    total 114688
// ---------------------------------------------------------------------------
__global__ void prep_kernel(const float* __restrict__ We1,
                            const float* __restrict__ We2,
                            const float* __restrict__ Wc1,
                            const float* __restrict__ Wn1,
                            const float* __restrict__ Wn2,
                            unsigned short* __restrict__ pW)
{
    const int idx = blockIdx.x * 256 + threadIdx.x;
    const float* src; int loc, nks, koff = 0;
    if (idx < 16384)       { src = We1; loc = idx;         nks = 4; }
    else if (idx < 32768)  { src = We1; loc = idx - 16384; nks = 4; koff = 128; }
    else if (idx < 49152)  { src = We2; loc = idx - 32768; nks = 4; }
    else if (idx < 65536)  { src = Wc1; loc = idx - 49152; nks = 4; }
    else if (idx < 98304)  { src = Wn1; loc = idx - 65536; nks = 8; }
    else                   { src = Wn2; loc = idx - 98304; nks = 4; }
    const int per_ct = nks * 512;
    const int ct = loc / per_ct;
    const int r  = loc % per_ct;
    const int ks = r >> 9;
    const int r2 = r & 511;
    const int ln = r2 >> 3;
    const int j  = r2 & 7;
    const int k  = ks * 32 + (ln >> 4) * 8 + j + koff;
    const int n  = ct * 16 + (ln & 15);
    pW[idx] = sbf(src[k * DD + n]);
}

// ---------------------------------------------------------------------------
// pq kernel: P = h @ We1a + be1, Q = h @ We1b  (both bf16 [N][128])
// 64 nodes/block, 4 waves.
// ---------------------------------------------------------------------------
__global__ __launch_bounds__(256, 2)
void pq_kernel(const float* __restrict__ h, const float* __restrict__ be1,
               const unsigned short* __restrict__ pW,
               unsigned short* __restrict__ P, unsigned short* __restrict__ Q)
{
    __shared__ __align__(16) unsigned short sAbuf[64 * 128];  // 16KB, 256B rows

    const int tid  = threadIdx.x;
    const int w    = tid >> 6;
    const int lane = tid & 63;
    const int g    = lane >> 4;
    const int l15  = lane & 15;
    const int n0   = blockIdx.x * TN;
    char* const sAb = (char*)sAbuf;

    // stage h tile bf16 swizzled
#pragma unroll
    for (int i = 0; i < 4; ++i) {
        const int idx = tid * 4 + i;          // 0..1023
        const int row = idx >> 4, c = idx & 15;
        const int n = n0 + row;
        float4 a = make_float4(0.f, 0.f, 0.f, 0.f);
        float4 b = make_float4(0.f, 0.f, 0.f, 0.f);
        if (n < NN) {
            a = *(const float4*)&h[(size_t)n * DD + c * 8];
            b = *(const float4*)&h[(size_t)n * DD + c * 8 + 4];
        }
        uint4 pk;
        pk.x = pkbf(a.x, a.y); pk.y = pkbf(a.z, a.w);
        pk.z = pkbf(b.x, b.y); pk.w = pkbf(b.z, b.w);
        *(uint4*)(sAb + row * 256 + ((c * 16) ^ ((row & 7) << 4))) = pk;
    }
    __syncthreads();

    f32x4 accP[4][2], accQ[4][2];
    {
        float be1c[2];
#pragma unroll
        for (int ctl = 0; ctl < 2; ++ctl)
            be1c[ctl] = be1[w * 32 + ctl * 16 + l15];
#pragma unroll
        for (int rt = 0; rt < 4; ++rt)
#pragma unroll
            for (int ctl = 0; ctl < 2; ++ctl)
#pragma unroll
                for (int j = 0; j < 4; ++j) {
                    accP[rt][ctl][j] = be1c[ctl];
                    accQ[rt][ctl][j] = 0.f;
                }
    }
    const unsigned short* pWa = pW;
    const unsigned short* pWb = pW + 16384;
#pragma unroll 1
    for (int ks = 0; ks < 4; ++ks) {
        bf16x8 a[4];
#pragma unroll
        for (int rt = 0; rt < 4; ++rt) {
            const int row = rt * 16 + l15;
            const int byc = g * 16 + ks * 64;
            a[rt] = *(const bf16x8*)(sAb + row * 256 + (byc ^ ((row & 7) << 4)));
        }
        const bf16x8 pa0 = *(const bf16x8*)&pWa[(((2 * w + 0) * 4 + ks) * 64 + lane) * 8];
        const bf16x8 pa1 = *(const bf16x8*)&pWa[(((2 * w + 1) * 4 + ks) * 64 + lane) * 8];
        const bf16x8 pb0 = *(const bf16x8*)&pWb[(((2 * w + 0) * 4 + ks) * 64 + lane) * 8];
        const bf16x8 pb1 = *(const bf16x8*)&pWb[(((2 * w + 1) * 4 + ks) * 64 + lane) * 8];
#pragma unroll
        for (int rt = 0; rt < 4; ++rt) {
            accP[rt][0] = __builtin_amdgcn_mfma_f32_16x16x32_bf16(a[rt], pa0, accP[rt][0], 0, 0, 0);
            accP[rt][1] = __builtin_amdgcn_mfma_f32_16x16x32_bf16(a[rt], pa1, accP[rt][1], 0, 0, 0);
            accQ[rt][0] = __builtin_amdgcn_mfma_f32_16x16x32_bf16(a[rt], pb0, accQ[rt][0], 0, 0, 0);
            accQ[rt][1] = __builtin_amdgcn_mfma_f32_16x16x32_bf16(a[rt], pb1, accQ[rt][1], 0, 0, 0);
        }
    }
#pragma unroll
    for (int rt = 0; rt < 4; ++rt)
#pragma unroll
        for (int ctl = 0; ctl < 2; ++ctl)
#pragma unroll
            for (int j = 0; j < 4; ++j) {
                const int row = rt * 16 + g * 4 + j;
                const int n = n0 + row;
                if (n < NN) {
                    const int col = w * 32 + ctl * 16 + l15;
                    P[(size_t)n * DD + col] = sbf(accP[rt][ctl][j]);
                    Q[(size_t)n * DD + col] = sbf(accQ[rt][ctl][j]);
                }
            }
}

// ---------------------------------------------------------------------------
// edge kernel: 128 row-sorted edges/block, 8 waves (512 thr), MFMA 16x16x32.
// GEMM1 hoisted: m1 = silu(P[row] + Q[col] + rad*wr). Wave w: rh=w>>2, cq=w&3.
// ---------------------------------------------------------------------------
__global__ __launch_bounds__(512, 6)
void edge_kernel(const int* __restrict__ ei,
                 const float* __restrict__ coord, const int* __restrict__ perm,
                 const unsigned short* __restrict__ P, const unsigned short* __restrict__ Q,
                 const float* __restrict__ We1,
                 const float* __restrict__ be2,
                 const float* __restrict__ Wa, const float* __restrict__ ba,
                 const float* __restrict__ bc1, const float* __restrict__ Wc2,
                 const unsigned short* __restrict__ pW,
                 float* __restrict__ agg_h, float* __restrict__ agg_c)
{
    // sM 32KB: m1 view then ef view (m1 fully consumed by GEMM2 before ef write)
    __shared__ __align__(16) unsigned short sM[128 * 128];
    __shared__ __align__(16) float sWred[4][128];
    __shared__ __align__(16) int   sRow[128];
    __shared__ int   sCol[128];
    __shared__ __align__(16) float sRad[128];
    __shared__ __align__(16) float sAtt[128];
    __shared__ float sCd[128][3];

    const int tid  = threadIdx.x;
    const int w    = tid >> 6;
    const int lane = tid & 63;
    const int g    = lane >> 4;
    const int l15  = lane & 15;
    const int rh   = w >> 2;          // row half (0/1)
    const int cq   = w & 3;           // col quarter
    const int rb   = rh * 64;         // row base
    const int e0g  = blockIdx.x * TEE;

    char* const sMb = (char*)sM;

    // ---- phase 0: permuted indices, coord diff, radial ----
    if (tid < TEE) {
        const int e = perm[e0g + tid];
        const int r = ei[e];
        const int c = ei[EE + e];
        sRow[tid] = r; sCol[tid] = c;
        const float dx = coord[r * 3 + 0] - coord[c * 3 + 0];
        const float dy = coord[r * 3 + 1] - coord[c * 3 + 1];
        const float dz = coord[r * 3 + 2] - coord[c * 3 + 2];
        sCd[tid][0] = dx; sCd[tid][1] = dy; sCd[tid][2] = dz;
        sRad[tid] = dx * dx + dy * dy + dz * dz;
    }
    __syncthreads();

    // ---- phase 1: m1 = silu(P[row] + Q[col] + rad*wr) -> sM (bf16 swizzled) ----
    {
        const int el  = tid >> 2;
        const int sub = tid & 3;
        const int rg = sRow[el], cg = sCol[el];
        const float rad = sRad[el];
        const unsigned short* Prow = P + (size_t)rg * DD;
        const unsigned short* Qrow = Q + (size_t)cg * DD;
        const float* We1r = We1 + 256 * DD;
#pragma unroll
        for (int i = 0; i < 4; ++i) {
            const int c = sub * 4 + i;                 // chunk of 8 cols
            const ushort8 pu = __builtin_bit_cast(ushort8, *(const bf16x8*)&Prow[c * 8]);
            const ushort8 qu = __builtin_bit_cast(ushort8, *(const bf16x8*)&Qrow[c * 8]);
            const float4 w0 = *(const float4*)&We1r[c * 8];
            const float4 w1 = *(const float4*)&We1r[c * 8 + 4];
            float x[8];
            x[0] = fmaf(rad, w0.x, bf2f(pu[0]) + bf2f(qu[0]));
            x[1] = fmaf(rad, w0.y, bf2f(pu[1]) + bf2f(qu[1]));
            x[2] = fmaf(rad, w0.z, bf2f(pu[2]) + bf2f(qu[2]));
            x[3] = fmaf(rad, w0.w, bf2f(pu[3]) + bf2f(qu[3]));
            x[4] = fmaf(rad, w1.x, bf2f(pu[4]) + bf2f(qu[4]));
            x[5] = fmaf(rad, w1.y, bf2f(pu[5]) + bf2f(qu[5]));
            x[6] = fmaf(rad, w1.z, bf2f(pu[6]) + bf2f(qu[6]));
            x[7] = fmaf(rad, w1.w, bf2f(pu[7]) + bf2f(qu[7]));
            uint4 pk;
            pk.x = pkbf(silu_f(x[0]), silu_f(x[1]));
            pk.y = pkbf(silu_f(x[2]), silu_f(x[3]));
            pk.z = pkbf(silu_f(x[4]), silu_f(x[5]));
            pk.w = pkbf(silu_f(x[6]), silu_f(x[7]));
            *(uint4*)(sMb + el * 256 + ((c * 16) ^ ((el & 7) << 4))) = pk;
        }
    }
    __syncthreads();

    f32x4 acc[4][2];

    // ---- phase 3: GEMM2  m = silu(m1 @ We2 + be2) ----
    {
        float be2c[2];
#pragma unroll
        for (int ctl = 0; ctl < 2; ++ctl)
            be2c[ctl] = be2[cq * 32 + ctl * 16 + l15];
#pragma unroll
        for (int rt = 0; rt < 4; ++rt)
#pragma unroll
            for (int ctl = 0; ctl < 2; ++ctl)
#pragma unroll
                for (int j = 0; j < 4; ++j)
                    acc[rt][ctl][j] = be2c[ctl];
        const unsigned short* pWe2 = pW + 32768;
#pragma unroll 1
        for (int ks = 0; ks < 4; ++ks) {
            bf16x8 a[4];
#pragma unroll
            for (int rt = 0; rt < 4; ++rt) {
                const int row = rb + rt * 16 + l15;
                const int byc = g * 16 + ks * 64;
                a[rt] = *(const bf16x8*)(sMb + row * 256 + (byc ^ ((row & 7) << 4)));
            }
            const bf16x8 b0 = *(const bf16x8*)&pWe2[(((2 * cq + 0) * 4 + ks) * 64 + lane) * 8];
            const bf16x8 b1 = *(const bf16x8*)&pWe2[(((2 * cq + 1) * 4 + ks) * 64 + lane) * 8];
#pragma unroll
            for (int rt = 0; rt < 4; ++rt) {
                acc[rt][0] = __builtin_amdgcn_mfma_f32_16x16x32_bf16(a[rt], b0, acc[rt][0], 0, 0, 0);
                acc[rt][1] = __builtin_amdgcn_mfma_f32_16x16x32_bf16(a[rt], b1, acc[rt][1], 0, 0, 0);
            }
        }
    }
#pragma unroll
    for (int rt = 0; rt < 4; ++rt)
#pragma unroll
        for (int ctl = 0; ctl < 2; ++ctl)
#pragma unroll
            for (int j = 0; j < 4; ++j)
                acc[rt][ctl][j] = silu_f(acc[rt][ctl][j]);

    // ---- attention: att = sigmoid(sum_col m*Wa + ba) ----
    {
        float wac[2];
#pragma unroll
        for (int ctl = 0; ctl < 2; ++ctl)
            wac[ctl] = Wa[cq * 32 + ctl * 16 + l15];
        float part[4][4];
#pragma unroll
        for (int rt = 0; rt < 4; ++rt)
#pragma unroll
            for (int j = 0; j < 4; ++j)
                part[rt][j] = fmaf(acc[rt][0][j], wac[0], acc[rt][1][j] * wac[1]);
#pragma unroll
        for (int msk = 1; msk < 16; msk <<= 1)
#pragma unroll
            for (int rt = 0; rt < 4; ++rt)
#pragma unroll
                for (int j = 0; j < 4; ++j)
                    part[rt][j] += __shfl_xor(part[rt][j], msk);
        if (l15 == 0) {
#pragma unroll
            for (int rt = 0; rt < 4; ++rt) {
                float4 p4 = make_float4(part[rt][0], part[rt][1], part[rt][2], part[rt][3]);
                *(float4*)&sWred[cq][rb + rt * 16 + g * 4] = p4;
            }
        }
    }
    __syncthreads();
    if (tid < TEE) {
        const float s = sWred[0][tid] + sWred[1][tid] + sWred[2][tid] + sWred[3][tid];
        sAtt[tid] = sigmoid_f(s + ba[0]);
    }
    __syncthreads();

    // ---- phase 4: edge_feat = m*att -> sM (bf16, same swizzle) ----
#pragma unroll
    for (int rt = 0; rt < 4; ++rt) {
        const float4 a4 = *(const float4*)&sAtt[rb + rt * 16 + g * 4];
        const float at[4] = {a4.x, a4.y, a4.z, a4.w};
#pragma unroll
        for (int ctl = 0; ctl < 2; ++ctl) {
            const int col = cq * 32 + ctl * 16 + l15;
#pragma unroll
            for (int j = 0; j < 4; ++j) {
                const float v = acc[rt][ctl][j] * at[j];
                const int row = rb + rt * 16 + g * 4 + j;
                *(unsigned short*)(sMb + row * 256 + ((col * 2) ^ ((row & 7) << 4))) = sbf(v);
            }
        }
    }
    __syncthreads();

    // ---- phase 5: GEMMc  w = (silu(ef @ Wc1 + bc1)) @ Wc2 ----
    {
        float bc1c[2];
#pragma unroll
        for (int ctl = 0; ctl < 2; ++ctl)
            bc1c[ctl] = bc1[cq * 32 + ctl * 16 + l15];
#pragma unroll
        for (int rt = 0; rt < 4; ++rt)
#pragma unroll
            for (int ctl = 0; ctl < 2; ++ctl)
#pragma unroll
                for (int j = 0; j < 4; ++j)
                    acc[rt][ctl][j] = bc1c[ctl];
        const unsigned short* pWc1 = pW + 49152;
#pragma unroll 1
        for (int ks = 0; ks < 4; ++ks) {
            bf16x8 a[4];
#pragma unroll
            for (int rt = 0; rt < 4; ++rt) {
                const int row = rb + rt * 16 + l15;
                const int byc = g * 16 + ks * 64;
                a[rt] = *(const bf16x8*)(sMb + row * 256 + (byc ^ ((row & 7) << 4)));
            }
            const bf16x8 b0 = *(const bf16x8*)&pWc1[(((2 * cq + 0) * 4 + ks) * 64 + lane) * 8];
            const bf16x8 b1 = *(const bf16x8*)&pWc1[(((2 * cq + 1) * 4 + ks) * 64 + lane) * 8];
#pragma unroll
            for (int rt = 0; rt < 4; ++rt) {
                acc[rt][0] = __builtin_amdgcn_mfma_f32_16x16x32_bf16(a[rt], b0, acc[rt][0], 0, 0, 0);
                acc[rt][1] = __builtin_amdgcn_mfma_f32_16x16x32_bf16(a[rt], b1, acc[rt][1], 0, 0, 0);
            }
        }
        float wcc[2];
#pragma unroll
        for (int ctl = 0; ctl < 2; ++ctl)
            wcc[ctl] = Wc2[cq * 32 + ctl * 16 + l15];
        float part[4][4];
#pragma unroll
        for (int rt = 0; rt < 4; ++rt)
#pragma unroll
            for (int j = 0; j < 4; ++j)
                part[rt][j] = fmaf(silu_f(acc[rt][0][j]), wcc[0], silu_f(acc[rt][1][j]) * wcc[1]);
#pragma unroll
        for (int msk = 1; msk < 16; msk <<= 1)
#pragma unroll
            for (int rt = 0; rt < 4; ++rt)
#pragma unroll
                for (int j = 0; j < 4; ++j)
                    part[rt][j] += __shfl_xor(part[rt][j], msk);
        if (l15 == 0) {
#pragma unroll
            for (int rt = 0; rt < 4; ++rt) {
                float4 p4 = make_float4(part[rt][0], part[rt][1], part[rt][2], part[rt][3]);
                *(float4*)&sWred[cq][rb + rt * 16 + g * 4] = p4;
            }
        }
    }
    __syncthreads();

    // ---- phase 6a: agg_h segmented reduce over sorted rows ----
    {
        const int col = tid & 127;
        const int seg = tid >> 7;           // 4 segments of 32 edges
        const int ebeg = seg * 32;
        float a = 0.f;
        int cur = sRow[ebeg];
#pragma unroll 1
        for (int e = ebeg; e < ebeg + 32; ++e) {
            const int r = sRow[e];
            if (r != cur) {
                atomic_add_f(&agg_h[(size_t)cur * DD + col], a);
                a = 0.f; cur = r;
            }
            const unsigned short u =
                *(const unsigned short*)(sMb + e * 256 + ((col * 2) ^ ((e & 7) << 4)));
            a += bf2f(u);
        }
        atomic_add_f(&agg_h[(size_t)cur * DD + col], a);
    }

    // ---- phase 6b: agg_c segmented reduce ----
    if (tid < 12) {
        const int c = tid % 3;
        const int seg = tid / 3;
        const int ebeg = seg * 32;
        float a = 0.f;
        int cur = sRow[ebeg];
#pragma unroll 1
        for (int e = ebeg; e < ebeg + 32; ++e) {
            const int r = sRow[e];
            if (r != cur) {
                atomic_add_f(&agg_c[cur * 3 + c], a);
                a = 0.f; cur = r;
            }
            const float wv = sWred[0][e] + sWred[1][e] + sWred[2][e] + sWred[3][e];
            a += sCd[e][c] * wv;
        }
        atomic_add_f(&agg_c[cur * 3 + c], a);
    }
}

// ---------------------------------------------------------------------------
// node kernel: 64 nodes/block, 4 waves, MFMA. [h | agg_h] @ Wn1 -> silu
// -> @ Wn2 + bn2 + h (residual). Coord out fused.
// ---------------------------------------------------------------------------
__global__ __launch_bounds__(256, 2)
void node_kernel(const float* __restrict__ h, const float* __restrict__ coord,
                 const float* __restrict__ bn1, const float* __restrict__ bn2,
                 const unsigned short* __restrict__ pW,
                 const float* __restrict__ agg_h, const float* __restrict__ agg_c,
                 const int* __restrict__ cnt,
                 float* __restrict__ hout, float* __restrict__ cout)
{
    __shared__ __align__(16) unsigned short sAbuf[64 * 256];   // 32KB

    const int tid  = threadIdx.x;
    const int w    = tid >> 6;
    const int lane = tid & 63;
    const int g    = lane >> 4;
    const int l15  = lane & 15;
    const int n0   = blockIdx.x * TN;
    char* const sAb = (char*)sAbuf;

    // ---- stage [h | agg_h] bf16, swizzled ----
    {
        const int halfsel = (lane >= 32) ? 1 : 0;
        const int bytec   = (lane & 31) * 8 + halfsel * 256;
        const float* src  = halfsel ? agg_h : h;
#pragma unroll 4
        for (int s = 0; s < 16; ++s) {
            const int row = w * 16 + s;
            const int n = n0 + row;
            float4 v = make_float4(0.f, 0.f, 0.f, 0.f);
            if (n < NN) v = *(const float4*)&src[(size_t)n * DD + (lane & 31) * 4];
            uint2 pk;
            pk.x = pkbf(v.x, v.y);
            pk.y = pkbf(v.z, v.w);
            *(uint2*)(sAb + row * 512 + (bytec ^ ((row & 7) << 4))) = pk;
        }
    }
    __syncthreads();

    f32x4 acc[4][2];

    // ---- GEMM1: silu([h|agg] @ Wn1 + bn1) ----
    {
        float bc[2];
#pragma unroll
        for (int ctl = 0; ctl < 2; ++ctl)
            bc[ctl] = bn1[w * 32 + ctl * 16 + l15];
#pragma unroll
        for (int rt = 0; rt < 4; ++rt)
#pragma unroll
            for (int ctl = 0; ctl < 2; ++ctl)
#pragma unroll
                for (int j = 0; j < 4; ++j)
                    acc[rt][ctl][j] = bc[ctl];
        const unsigned short* pWn1 = pW + 65536;
#pragma unroll 1
        for (int ks = 0; ks < 8; ++ks) {
            bf16x8 a[4];
#pragma unroll
            for (int rt = 0; rt < 4; ++rt) {
                const int row = rt * 16 + l15;
                const int byc = g * 16 + ks * 64;
                a[rt] = *(const bf16x8*)(sAb + row * 512 + (byc ^ ((row & 7) << 4)));
            }
            const bf16x8 b0 = *(const bf16x8*)&pWn1[(((2 * w + 0) * 8 + ks) * 64 + lane) * 8];
            const bf16x8 b1 = *(const bf16x8*)&pWn1[(((2 * w + 1) * 8 + ks) * 64 + lane) * 8];
#pragma unroll
            for (int rt = 0; rt < 4; ++rt) {
                acc[rt][0] = __builtin_amdgcn_mfma_f32_16x16x32_bf16(a[rt], b0, acc[rt][0], 0, 0, 0);
                acc[rt][1] = __builtin_amdgcn_mfma_f32_16x16x32_bf16(a[rt], b1, acc[rt][1], 0, 0, 0);
            }
        }
    }
    __syncthreads();
#pragma unroll
    for (int rt = 0; rt < 4; ++rt)
#pragma unroll
        for (int ctl = 0; ctl < 2; ++ctl)
#pragma unroll
            for (int j = 0; j < 4; ++j) {
                const int row = rt * 16 + g * 4 + j;
                const int col = w * 32 + ctl * 16 + l15;
                *(unsigned short*)(sAb + row * 256 + ((col * 2) ^ ((row & 7) << 4)))
                    = sbf(silu_f(acc[rt][ctl][j]));
            }
    __syncthreads();

    // ---- GEMM2 + bias + residual ----
    {
        float bc[2];
#pragma unroll
        for (int ctl = 0; ctl < 2; ++ctl)
            bc[ctl] = bn2[w * 32 + ctl * 16 + l15];
#pragma unroll
        for (int rt = 0; rt < 4; ++rt)
#pragma unroll
            for (int ctl = 0; ctl < 2; ++ctl)
#pragma unroll
                for (int j = 0; j < 4; ++j)
                    acc[rt][ctl][j] = bc[ctl];
        const unsigned short* pWn2 = pW + 98304;
#pragma unroll 1
        for (int ks = 0; ks < 4; ++ks) {
            bf16x8 a[4];
#pragma unroll
            for (int rt = 0; rt < 4; ++rt) {
                const int row = rt * 16 + l15;
                const int byc = g * 16 + ks * 64;
                a[rt] = *(const bf16x8*)(sAb + row * 256 + (byc ^ ((row & 7) << 4)));
            }
            const bf16x8 b0 = *(const bf16x8*)&pWn2[(((2 * w + 0) * 4 + ks) * 64 + lane) * 8];
            const bf16x8 b1 = *(const bf16x8*)&pWn2[(((2 * w + 1) * 4 + ks) * 64 + lane) * 8];
#pragma unroll
            for (int rt = 0; rt < 4; ++rt) {
                acc[rt][0] = __builtin_amdgcn_mfma_f32_16x16x32_bf16(a[rt], b0, acc[rt][0], 0, 0, 0);
                acc[rt][1] = __builtin_amdgcn_mfma_f32_16x16x32_bf16(a[rt], b1, acc[rt][1], 0, 0, 0);
            }
        }
    }
#pragma unroll
    for (int rt = 0; rt < 4; ++rt)
#pragma unroll
        for (int ctl = 0; ctl < 2; ++ctl)
#pragma unroll
            for (int j = 0; j < 4; ++j) {
                const int row = rt * 16 + g * 4 + j;
                const int n = n0 + row;
                if (n < NN) {
                    const int col = w * 32 + ctl * 16 + l15;
                    hout[(size_t)n * DD + col] = h[(size_t)n * DD + col] + acc[rt][ctl][j];
                }
            }

    // ---- coord out ----
    if (tid < TN * 3) {
        const int e = tid / 3, c = tid % 3;
        const int n = n0 + e;
        if (n < NN) {
            const float cn = fmaxf((float)cnt[n], 1.0f);
            cout[n * 3 + c] = coord[n * 3 + c] + agg_c[n * 3 + c] / cn;
        }
    }
}

extern "C" void kernel_launch(void* const* d_in, const int* in_sizes, int n_in,
                              void* d_out, int out_size, void* d_ws, size_t ws_size,
                              hipStream_t stream)
{
    const float* h     = (const float*)d_in[0];
    const int*   ei    = (const int*)  d_in[1];
    const float* coord = (const float*)d_in[2];
    const float* We1   = (const float*)d_in[3];
    const float* be1   = (const float*)d_in[4];
    const float* We2   = (const float*)d_in[5];
    const float* be2   = (const float*)d_in[6];
    const float* Wa    = (const float*)d_in[7];
    const float* ba    = (const float*)d_in[8];
    const float* Wn1   = (const float*)d_in[9];
    const float* bn1   = (const float*)d_in[10];
    const float* Wn2   = (const float*)d_in[11];
    const float* bn2   = (const float*)d_in[12];
    const float* Wc1   = (const float*)d_in[13];
    const float* bc1   = (const float*)d_in[14];
    const float* Wc2   = (const float*)d_in[15];

    // ws layout (16B-aligned chunks)
    float* agg_h   = (float*)d_ws;                   // 1,280,000 f
    float* agg_c   = agg_h + (size_t)NN * DD;        //    30,000 f
    int*   cnt_i   = (int*)(agg_c + (size_t)NN * 3); //    10,000 i
    int*   tmp_i   = cnt_i + NN;                     //    10,000 i
    int*   offs    = tmp_i + NN;                     //    10,004 i (padded to 10,016)
    int*   perm    = offs + 10016;                   //   320,000 i
    unsigned short* pW = (unsigned short*)(perm + EE);     // 114,688 u16
    unsigned short* P  = pW + 114688;                      // 1,280,000 u16
    unsigned short* Q  = P + (size_t)NN * DD;              // 1,280,000 u16

    (void)hipMemsetAsync(d_ws, 0, (size_t)(NN * DD + NN * 3 + NN + NN) * sizeof(float), stream);

    hist_kernel<<<(EE + 255) / 256, 256, 0, stream>>>(ei, cnt_i);
    scan_kernel<<<1, 512, 0, stream>>>(cnt_i, offs);
    scatter_kernel<<<(EE + 255) / 256, 256, 0, stream>>>(ei, offs, tmp_i, perm);
    prep_kernel<<<448, 256, 0, stream>>>(We1, We2, Wc1, Wn1, Wn2, pW);
    pq_kernel<<<(NN + TN - 1) / TN, 256, 0, stream>>>(h, be1, pW, P, Q);

    edge_kernel<<<EE / TEE, 512, 0, stream>>>(ei, coord, perm, P, Q, We1, be2,
                                              Wa, ba, bc1, Wc2, pW, agg_h, agg_c);

    float* hout = (float*)d_out;
    float* cout = hout + (size_t)NN * DD;
    node_kernel<<<(NN + TN - 1) / TN, 256, 0, stream>>>(h, coord, bn1, bn2, pW,
                                                        agg_h, agg_c, cnt_i, hout, cout);
}